// Round 7
// baseline (986.049 us; speedup 1.0000x reference)
//
#include <hip/hip_runtime.h>

// PointNet++ SA module on MI355X.
// Pipeline: cvt (weight transpose->fp16) ; P = x@W1a+b1 (fp16) ; FPS ; ball query ; fused MLP+max.
// Layer1 trick: x_j@W1a precomputed per point (16x reuse); pair-wise part is only rel@W1b.
// Layers 2/3 use v_mfma_f32_16x16x32_f16 (no fp32 MFMA on CDNA4).
// R1: FPS: no global stores in the serial loop (vmcnt(0) drain at every barrier).
// R2: FPS: 4 waves (1/SIMD), DPP f32 max reduce; argmax via ballot+ctz+readlane.
// R5: FPS: (a) packed-fp32 distance update (ext_vector float2, contract(off) for exact
//     JAX rounding; backend may select v_pk_add/mul_f32, halving update issue);
//     (b) barrier-free cross-wave merge: per-step pkey[1024][4] slots + volatile poll
//     (key never 0), removing s_barrier from the 1024-step serial chain.
// R6/R7: broker timeouts — identical resubmit for a clean measurement.

#define NB 8
#define NP 4096
#define MP 1024
#define NC 8192         // NB*MP centroids
#define CIN 64
#define D1 128
#define D2 128
#define D3 256
#define CAP 512         // ball-query candidate capacity (E[count]~137, 32 sigma safe)

static constexpr float R2F = 0.04f;   // (0.2)^2 in f32, bit-identical to jnp promotion

typedef _Float16 f16;
typedef _Float16 half8 __attribute__((ext_vector_type(8)));
typedef float floatx4 __attribute__((ext_vector_type(4)));
typedef float f32x2 __attribute__((ext_vector_type(2)));
typedef unsigned long long u64;

// d_out layout (floats): [NC*256 out][NC*3 pos_out][NC batch_out]
#define OUT1 ((size_t)NC * D3)
#define OUT2 (OUT1 + (size_t)NC * 3)

// ---------------- weight conversion ----------------
__global__ void cvt_kernel(const float* __restrict__ W1, const float* __restrict__ W2,
                           const float* __restrict__ W3, f16* __restrict__ W2t,
                           f16* __restrict__ W3t, float* __restrict__ W1b) {
  const int stride = gridDim.x * blockDim.x;
  const int i = blockIdx.x * blockDim.x + threadIdx.x;
  for (int e = i; e < D1 * D2; e += stride) {      // W2t[c][k] = W2[k][c]
    int c = e >> 7, k = e & 127;
    W2t[c * 128 + k] = (f16)W2[k * D2 + c];
  }
  for (int e = i; e < D2 * D3; e += stride) {      // W3t[c][k] = W3[k][c]
    int c = e >> 7, k = e & 127;
    W3t[c * 128 + k] = (f16)W3[k * D3 + c];
  }
  for (int e = i; e < 3 * D1; e += stride) W1b[e] = W1[64 * D1 + e];  // rel rows of W1
}

// ---------------- P = x @ W1[0:64] + b1 (fp16 out) ----------------
__launch_bounds__(256)
__global__ void pk_kernel(const float* __restrict__ x, const float* __restrict__ W1,
                          const float* __restrict__ b1, f16* __restrict__ P) {
  __shared__ float wl[CIN * D1];   // 32KB
  __shared__ float xl[32 * CIN];   // 8KB
  const int t = threadIdx.x;
  const int r0 = blockIdx.x * 32;
  for (int e = t; e < CIN * D1; e += 256) wl[e] = W1[e];
  for (int e = t; e < 32 * CIN; e += 256)
    xl[e] = x[(size_t)(r0 + (e >> 6)) * CIN + (e & 63)];
  __syncthreads();
  const int c = t & 127;
  const int rh = t >> 7;           // wave-uniform (waves 0,1 -> 0; waves 2,3 -> 1)
  const float bc = b1[c];
  for (int rr = 0; rr < 32; rr += 2) {
    const int r = rr + rh;
    float acc = bc;
    #pragma unroll
    for (int k = 0; k < CIN; ++k) acc = __fmaf_rn(xl[r * CIN + k], wl[k * D1 + c], acc);
    P[(size_t)(r0 + r) * D1 + c] = (f16)acc;
  }
}

// ---------------- FPS: 1 block (4 waves) per cloud ----------------
template<int CTRL>
__device__ __forceinline__ float dppmax(float v) {
  const int iv = __builtin_bit_cast(int, v);
  const int sh = __builtin_amdgcn_update_dpp(iv, iv, CTRL, 0xf, 0xf, false);
  return fmaxf(v, __builtin_bit_cast(float, sh));
}

__launch_bounds__(256)
__global__ void fps_kernel(const float* __restrict__ pos, float* __restrict__ qpos,
                           float* __restrict__ dout) {
  #pragma clang fp contract(off)
  __shared__ float ldspos[NP * 3];       // 48KB: whole cloud resident
  __shared__ u64 pkey[MP][4];            // 32KB: per-step slots, written exactly once
  __shared__ int cidx[MP];               // 4KB winner log, flushed in epilogue
  const int b = blockIdx.x;
  const int t = threadIdx.x;
  const int lane = t & 63, wv = t >> 6;
  for (int e = t; e < MP * 4; e += 256) ((u64*)pkey)[e] = 0ull;
  for (int e = t; e < NP * 3; e += 256) ldspos[e] = pos[(size_t)b * NP * 3 + e];
  __syncthreads();
  // blocked mapping: thread t owns points [t*16, t*16+16); pair i = {2i, 2i+1} local
  f32x2 px[8], py[8], pz[8], dv[8];
  #pragma unroll
  for (int i = 0; i < 8; ++i) {
    const int p = t * 16 + 2 * i;
    px[i] = (f32x2){ldspos[p * 3 + 0], ldspos[p * 3 + 3]};
    py[i] = (f32x2){ldspos[p * 3 + 1], ldspos[p * 3 + 4]};
    pz[i] = (f32x2){ldspos[p * 3 + 2], ldspos[p * 3 + 5]};
    dv[i] = INFINITY;
  }
  int g = 0;
  for (int step = 0; step < MP; ++step) {
    if (t == 0) cidx[step] = g;
    const float cx = ldspos[g * 3 + 0], cy = ldspos[g * 3 + 1], cz = ldspos[g * 3 + 2];
    const f32x2 cx2 = cx, cy2 = cy, cz2 = cz;
    // packed distance update, contract(off) -> separate rn mul/add, exact JAX order
    f32x2 lvv = -1.0f;
    #pragma unroll
    for (int i = 0; i < 8; ++i) {
      const f32x2 dx = px[i] - cx2;
      const f32x2 dy = py[i] - cy2;
      const f32x2 dz = pz[i] - cz2;
      const f32x2 nd = (dx * dx + dy * dy) + dz * dz;
      dv[i] = __builtin_elementwise_min(dv[i], nd);
      lvv = __builtin_elementwise_max(lvv, dv[i]);
    }
    const float lv = fmaxf(lvv.x, lvv.y);
    // lane-local argmax, lowest-i tie-break (descending overwrite)
    int li = 15;
    #pragma unroll
    for (int i = 14; i >= 0; --i) {
      const float di = (i & 1) ? dv[i >> 1].y : dv[i >> 1].x;
      li = (di == lv) ? i : li;
    }
    // in-wave max via DPP (VALU pipe): result in lane 63
    float wm = lv;
    wm = dppmax<0xB1>(wm);    // quad_perm [1,0,3,2]
    wm = dppmax<0x4E>(wm);    // quad_perm [2,3,0,1]
    wm = dppmax<0x141>(wm);   // row_half_mirror
    wm = dppmax<0x140>(wm);   // row_mirror
    wm = dppmax<0x142>(wm);   // row_bcast:15
    wm = dppmax<0x143>(wm);   // row_bcast:31
    const float M = __builtin_bit_cast(float,
        __builtin_amdgcn_readlane(__builtin_bit_cast(int, wm), 63));
    // wave argmax: lowest lane holding M, then its lowest i
    const u64 bal = __ballot(lv == M);
    const int Ls = (int)__builtin_ctzll(bal);
    const int sli = __builtin_amdgcn_readlane(li, Ls);
    const int gw = ((wv << 6) + Ls) * 16 + sli;   // wave winner global idx
    // key = (d2_bits<<32)|~gw : max key == max d2, tie -> lowest idx; never 0
    if (lane == 0)
      *(volatile u64*)&pkey[step][wv] =
          ((u64)__float_as_uint(M) << 32) | (unsigned int)~gw;
    // barrier-free merge: poll the 4 per-step slots (same-address broadcast reads)
    volatile const u64* pk = &pkey[step][0];
    u64 k0, k1, k2, k3;
    do { k0 = pk[0]; k1 = pk[1]; k2 = pk[2]; k3 = pk[3]; }
    while (k0 == 0ull || k1 == 0ull || k2 == 0ull || k3 == 0ull);
    u64 ba = k0 > k1 ? k0 : k1;
    const u64 bb = k2 > k3 ? k2 : k3;
    ba = ba > bb ? ba : bb;
    g = (int)~(unsigned int)ba;
  }
  __syncthreads();
  // epilogue: flush all centroid outputs in parallel
  for (int s = t; s < MP; s += 256) {
    const int ci = (b << 10) + s;
    const int p = cidx[s];
    const float cx = ldspos[p * 3 + 0], cy = ldspos[p * 3 + 1], cz = ldspos[p * 3 + 2];
    qpos[ci * 3 + 0] = cx; qpos[ci * 3 + 1] = cy; qpos[ci * 3 + 2] = cz;
    dout[OUT1 + (size_t)ci * 3 + 0] = cx;
    dout[OUT1 + (size_t)ci * 3 + 1] = cy;
    dout[OUT1 + (size_t)ci * 3 + 2] = cz;
    dout[OUT2 + ci] = (float)b;
  }
}

// ---------------- ball query: 1 wave per centroid, exact k-NN within R ----------------
__launch_bounds__(256)
__global__ void ballq_kernel(const float* __restrict__ pos, const float* __restrict__ qpos,
                             int* __restrict__ nbr) {
  __shared__ unsigned long long list[4][CAP];   // 16KB
  const int t = threadIdx.x;
  const int wv = t >> 6, lane = t & 63;
  const int ci = blockIdx.x * 4 + wv;
  const int b = ci >> 10;
  const int base = b * NP;
  const float qx = qpos[ci * 3 + 0], qy = qpos[ci * 3 + 1], qz = qpos[ci * 3 + 2];
  int cnt = 0;
  for (int chunk = 0; chunk < NP / 64; ++chunk) {
    const int p = chunk * 64 + lane;
    const float x = pos[(size_t)(base + p) * 3 + 0];
    const float y = pos[(size_t)(base + p) * 3 + 1];
    const float z = pos[(size_t)(base + p) * 3 + 2];
    const float dx = __fsub_rn(qx, x), dy = __fsub_rn(qy, y), dz = __fsub_rn(qz, z);
    const float d2 = __fadd_rn(__fadd_rn(__fmul_rn(dx, dx), __fmul_rn(dy, dy)),
                               __fmul_rn(dz, dz));
    const bool in = d2 <= R2F;
    const unsigned long long mask = __ballot(in);
    if (in) {
      const int slot = cnt + __popcll(mask & ((1ull << lane) - 1ull));
      if (slot < CAP)
        list[wv][slot] = ((unsigned long long)__float_as_uint(d2) << 32) | (unsigned int)p;
    }
    cnt += __popcll(mask);
  }
  const int cntc = cnt < CAP ? cnt : CAP;
  for (int s = cntc + lane; s < CAP; s += 64) list[wv][s] = ~0ull;
  __syncthreads();
  // bitonic ascending sort of (d2_bits, idx) -> exact top_k tie-break (lowest idx)
  for (int ks = 2; ks <= CAP; ks <<= 1) {
    for (int jj = ks >> 1; jj > 0; jj >>= 1) {
      for (int i = lane; i < CAP; i += 64) {
        const int partner = i ^ jj;
        if (partner > i) {
          const bool up = ((i & ks) == 0);
          const unsigned long long a = list[wv][i], c = list[wv][partner];
          if (up ? (a > c) : (a < c)) { list[wv][i] = c; list[wv][partner] = a; }
        }
      }
      __syncthreads();
    }
  }
  const unsigned long long e = list[wv][lane];
  const int idx = (int)(e & 0xFFFFFFFFull);
  nbr[(ci << 6) + lane] = (lane < cntc) ? idx : -1;
}

// ---------------- fused MLP + max aggregation: 1 block (4 waves) per centroid ----------------
__launch_bounds__(256)
__global__ void mlp_kernel(const float* __restrict__ pos, const float* __restrict__ qpos,
                           const int* __restrict__ nbr, const f16* __restrict__ P,
                           const float* __restrict__ W1b, const f16* __restrict__ W2t,
                           const float* __restrict__ b2c, const f16* __restrict__ W3t,
                           const float* __restrict__ b3c, float* __restrict__ out) {
  __shared__ f16 h1s[64 * 128];   // 16KB, element (r,k) at r*128 + (k ^ ((r&7)<<3))
  __shared__ f16 h2s[64 * 128];   // 16KB, same swizzle
  const int ci = blockIdx.x;
  const int base = (ci >> 10) << 12;
  const int t = threadIdx.x;
  const int lane = t & 63;
  const int wv = __builtin_amdgcn_readfirstlane((int)(t >> 6));
  const int m = lane & 15, qq = lane >> 4;

  const int j = nbr[(ci << 6) + lane];
  const bool valid = j >= 0;
  const int cnt = __popcll(__ballot(valid));   // valid rows are exactly [0, cnt)
  const int j0 = __shfl(j, 0);
  const int jjn = valid ? j : (j0 >= 0 ? j0 : 0);

  const float qx = qpos[ci * 3 + 0], qy = qpos[ci * 3 + 1], qz = qpos[ci * 3 + 2];
  const float rx = pos[(size_t)(base + jjn) * 3 + 0] - qx;
  const float ry = pos[(size_t)(base + jjn) * 3 + 1] - qy;
  const float rz = pos[(size_t)(base + jjn) * 3 + 2] - qz;

  // ---- phase 1: h1 = relu(P[j] + rel@W1b), cols [wv*32, wv*32+32), lane = row ----
  {
    const f16* Prow = P + (size_t)(base + jjn) * D1;
    const int r = lane;
    #pragma unroll
    for (int c8 = 0; c8 < 4; ++c8) {
      const int c0 = wv * 32 + c8 * 8;
      const half8 pv = *(const half8*)(Prow + c0);
      half8 hv;
      #pragma unroll
      for (int u = 0; u < 8; ++u) {
        const int c = c0 + u;
        float v = (float)pv[u] + rx * W1b[c] + ry * W1b[128 + c] + rz * W1b[256 + c];
        hv[u] = (f16)fmaxf(v, 0.0f);
      }
      *(half8*)(h1s + r * 128 + (c0 ^ ((r & 7) << 3))) = hv;
    }
  }
  __syncthreads();

  // ---- phase 2: h2 = relu(h1 @ W2 + b2), wave computes cols [wv*32, wv*32+32) ----
  {
    floatx4 acc[2][4];
    #pragma unroll
    for (int cs = 0; cs < 2; ++cs)
      #pragma unroll
      for (int rt = 0; rt < 4; ++rt) acc[cs][rt] = floatx4{0.f, 0.f, 0.f, 0.f};
    #pragma unroll
    for (int ks = 0; ks < 4; ++ks) {
      const int kk = ks * 32 + qq * 8;
      half8 af[4];
      #pragma unroll
      for (int rt = 0; rt < 4; ++rt) {
        const int r = rt * 16 + m;
        af[rt] = *(const half8*)(h1s + r * 128 + (kk ^ ((r & 7) << 3)));
      }
      half8 bf[2];
      #pragma unroll
      for (int cs = 0; cs < 2; ++cs) {
        const int c = (wv * 2 + cs) * 16 + m;
        bf[cs] = *(const half8*)(W2t + (size_t)c * 128 + kk);
      }
      #pragma unroll
      for (int cs = 0; cs < 2; ++cs)
        #pragma unroll
        for (int rt = 0; rt < 4; ++rt)
          acc[cs][rt] = __builtin_amdgcn_mfma_f32_16x16x32_f16(af[rt], bf[cs], acc[cs][rt], 0, 0, 0);
    }
    #pragma unroll
    for (int cs = 0; cs < 2; ++cs) {
      const int c = (wv * 2 + cs) * 16 + m;
      const float bias = b2c[c];
      #pragma unroll
      for (int rt = 0; rt < 4; ++rt) {
        #pragma unroll
        for (int u = 0; u < 4; ++u) {
          const int r = rt * 16 + qq * 4 + u;   // C layout: col=lane&15, row=(lane>>4)*4+u
          h2s[r * 128 + (c ^ ((r & 7) << 3))] = (f16)fmaxf(acc[cs][rt][u] + bias, 0.0f);
        }
      }
    }
  }
  __syncthreads();

  // ---- phase 3: h3 = relu(h2 @ W3 + b3); masked max over rows; wave cols [wv*64,+64) ----
  {
    floatx4 acc[4][4];
    #pragma unroll
    for (int ct = 0; ct < 4; ++ct)
      #pragma unroll
      for (int rt = 0; rt < 4; ++rt) acc[ct][rt] = floatx4{0.f, 0.f, 0.f, 0.f};
    #pragma unroll
    for (int ks = 0; ks < 4; ++ks) {
      const int kk = ks * 32 + qq * 8;
      half8 af[4];
      #pragma unroll
      for (int rt = 0; rt < 4; ++rt) {
        const int r = rt * 16 + m;
        af[rt] = *(const half8*)(h2s + r * 128 + (kk ^ ((r & 7) << 3)));
      }
      half8 bf[4];
      #pragma unroll
      for (int ct = 0; ct < 4; ++ct) {
        const int c = (wv * 4 + ct) * 16 + m;
        bf[ct] = *(const half8*)(W3t + (size_t)c * 128 + kk);
      }
      #pragma unroll
      for (int ct = 0; ct < 4; ++ct)
        #pragma unroll
        for (int rt = 0; rt < 4; ++rt)
          acc[ct][rt] = __builtin_amdgcn_mfma_f32_16x16x32_f16(af[rt], bf[ct], acc[ct][rt], 0, 0, 0);
    }
    #pragma unroll
    for (int ct = 0; ct < 4; ++ct) {
      const int c = (wv * 4 + ct) * 16 + m;
      const float bias = b3c[c];
      float mx = -INFINITY;
      #pragma unroll
      for (int rt = 0; rt < 4; ++rt) {
        #pragma unroll
        for (int u = 0; u < 4; ++u) {
          const int r = rt * 16 + qq * 4 + u;
          float v = fmaxf(acc[ct][rt][u] + bias, 0.0f);
          v = (r < cnt) ? v : -INFINITY;
          mx = fmaxf(mx, v);
        }
      }
      mx = fmaxf(mx, __shfl_xor(mx, 16));
      mx = fmaxf(mx, __shfl_xor(mx, 32));
      mx = (cnt > 0) ? mx : 0.0f;
      if (qq == 0) out[(size_t)ci * D3 + c] = mx;
    }
  }
}

extern "C" void kernel_launch(void* const* d_in, const int* in_sizes, int n_in,
                              void* d_out, int out_size, void* d_ws, size_t ws_size,
                              hipStream_t stream) {
  const float* x   = (const float*)d_in[0];
  const float* pos = (const float*)d_in[1];
  // d_in[2] = batch: layout known (sorted, NP per cloud) -> unused
  const float* W1 = (const float*)d_in[3];
  const float* b1 = (const float*)d_in[4];
  const float* W2 = (const float*)d_in[5];
  const float* b2 = (const float*)d_in[6];
  const float* W3 = (const float*)d_in[7];
  const float* b3 = (const float*)d_in[8];
  float* out = (float*)d_out;

  char* ws = (char*)d_ws;
  f16*   P    = (f16*)  (ws + 0);          // 8,388,608 B
  float* qpos = (float*)(ws + 8388608);    //    98,304 B
  int*   nbr  = (int*)  (ws + 8486912);    // 2,097,152 B
  f16*   W2t  = (f16*)  (ws + 10584064);   //    32,768 B
  f16*   W3t  = (f16*)  (ws + 10616832);   //    65,536 B
  float* W1b  = (float*)(ws + 10682368);   //     1,536 B   (total ~10.2 MB)

  cvt_kernel<<<64, 256, 0, stream>>>(W1, W2, W3, W2t, W3t, W1b);
  pk_kernel<<<NB * NP / 32, 256, 0, stream>>>(x, W1, b1, P);
  fps_kernel<<<NB, 256, 0, stream>>>(pos, qpos, out);
  ballq_kernel<<<NC / 4, 256, 0, stream>>>(pos, qpos, nbr);
  mlp_kernel<<<NC, 256, 0, stream>>>(pos, qpos, nbr, P, W1b, W2t, b2, W3t, b3, out);
}

// Round 8
// 860.466 us; speedup vs baseline: 1.1459x; 1.1459x over previous
//
#include <hip/hip_runtime.h>

// PointNet++ SA module on MI355X.
// Pipeline: fused{cvt, pk, FPS} ; ball query ; fused MLP+max.
// Layer1 trick: x_j@W1a precomputed per point (16x reuse); pair-wise part is only rel@W1b.
// Layers 2/3 use v_mfma_f32_16x16x32_f16 (no fp32 MFMA on CDNA4).
// R1: FPS: no global stores in the serial loop (vmcnt(0) drain at every barrier).
// R2/R4: FPS: 4 waves (1/SIMD), scalar update, DPP f32 max reduce; argmax via
//     ballot+ctz+readlane; single barrier/step. 549us, VGPR 68. PROVEN.
// R5: REGRESSED (660us): f32x2 packing scalarized (no v_pk_min/max_f32 on gfx950,
//     VGPR 68->132) and poll-merge beat by s_barrier. Reverted.
// R8: fuse {fps | pk | cvt} into one kernel on disjoint blockIdx ranges — pk/cvt are
//     independent of fps and hide under its 550us tail (fps uses 8 of 256 CUs).

#define NB 8
#define NP 4096
#define MP 1024
#define NC 8192         // NB*MP centroids
#define CIN 64
#define D1 128
#define D2 128
#define D3 256
#define CAP 512         // ball-query candidate capacity (E[count]~137, 32 sigma safe)

static constexpr float R2F = 0.04f;   // (0.2)^2 in f32, bit-identical to jnp promotion

typedef _Float16 f16;
typedef _Float16 half8 __attribute__((ext_vector_type(8)));
typedef float floatx4 __attribute__((ext_vector_type(4)));
typedef unsigned long long u64;

// d_out layout (floats): [NC*256 out][NC*3 pos_out][NC batch_out]
#define OUT1 ((size_t)NC * D3)
#define OUT2 (OUT1 + (size_t)NC * 3)

// ---------------- fused front end: blocks 0-7 FPS, 8-1031 pk, 1032-1095 cvt ----------
template<int CTRL>
__device__ __forceinline__ float dppmax(float v) {
  const int iv = __builtin_bit_cast(int, v);
  const int sh = __builtin_amdgcn_update_dpp(iv, iv, CTRL, 0xf, 0xf, false);
  return fmaxf(v, __builtin_bit_cast(float, sh));
}

struct FpsS { float ldspos[NP * 3]; u64 pkey[2][4]; int cidx[MP]; };   // 53312 B
struct PkS  { float wl[CIN * D1]; float xl[32 * CIN]; };               // 40960 B

__launch_bounds__(256)
__global__ void front_kernel(const float* __restrict__ pos, const float* __restrict__ x,
                             const float* __restrict__ W1, const float* __restrict__ b1,
                             const float* __restrict__ W2, const float* __restrict__ W3,
                             float* __restrict__ qpos, f16* __restrict__ P,
                             f16* __restrict__ W2t, f16* __restrict__ W3t,
                             float* __restrict__ W1b, float* __restrict__ dout) {
  __shared__ __align__(16) char raw[sizeof(FpsS)];
  const int bid = blockIdx.x;
  const int t = threadIdx.x;

  if (bid < NB) {
    // ================= FPS: 1 block (4 waves, 1/SIMD) per cloud =================
    FpsS& S = *reinterpret_cast<FpsS*>(raw);
    const int b = bid;
    const int lane = t & 63, wv = t >> 6;
    for (int e = t; e < NP * 3; e += 256) S.ldspos[e] = pos[(size_t)b * NP * 3 + e];
    __syncthreads();
    // blocked mapping: thread t owns points [t*16, t*16+16) -> lane order == index order
    float px[16], py[16], pz[16], d[16];
    #pragma unroll
    for (int i = 0; i < 16; ++i) {
      const int p = t * 16 + i;
      px[i] = S.ldspos[p * 3 + 0]; py[i] = S.ldspos[p * 3 + 1]; pz[i] = S.ldspos[p * 3 + 2];
      d[i] = INFINITY;
    }
    int g = 0;
    for (int step = 0; step < MP; ++step) {
      if (t == 0) S.cidx[step] = g;
      const float cx = S.ldspos[g * 3 + 0], cy = S.ldspos[g * 3 + 1], cz = S.ldspos[g * 3 + 2];
      // update d (exact JAX op order); track lane max
      float lv = -1.0f;
      #pragma unroll
      for (int i = 0; i < 16; ++i) {
        const float dx = __fsub_rn(px[i], cx);
        const float dy = __fsub_rn(py[i], cy);
        const float dz = __fsub_rn(pz[i], cz);
        const float nd = __fadd_rn(__fadd_rn(__fmul_rn(dx, dx), __fmul_rn(dy, dy)),
                                   __fmul_rn(dz, dz));
        d[i] = fminf(d[i], nd);
        lv = fmaxf(lv, d[i]);
      }
      // lane-local argmax, lowest-i tie-break (descending overwrite)
      int li = 15;
      #pragma unroll
      for (int i = 14; i >= 0; --i) li = (d[i] == lv) ? i : li;
      // in-wave max via DPP (VALU pipe): result in lane 63
      float wm = lv;
      wm = dppmax<0xB1>(wm);    // quad_perm [1,0,3,2]
      wm = dppmax<0x4E>(wm);    // quad_perm [2,3,0,1]
      wm = dppmax<0x141>(wm);   // row_half_mirror
      wm = dppmax<0x140>(wm);   // row_mirror
      wm = dppmax<0x142>(wm);   // row_bcast:15
      wm = dppmax<0x143>(wm);   // row_bcast:31
      const float M = __builtin_bit_cast(float,
          __builtin_amdgcn_readlane(__builtin_bit_cast(int, wm), 63));
      // wave argmax: lowest lane holding M, then its lowest i
      const u64 bal = __ballot(lv == M);
      const int Ls = (int)__builtin_ctzll(bal);
      const int sli = __builtin_amdgcn_readlane(li, Ls);
      const int gw = ((wv << 6) + Ls) * 16 + sli;   // wave winner global idx
      if (lane == 0)
        S.pkey[step & 1][wv] = ((u64)__float_as_uint(M) << 32) | (unsigned int)~gw;
      __syncthreads();
      // cross-wave: 4 keys, 3 u64 compare-selects (redundant in every thread)
      u64 best = S.pkey[step & 1][0];
      #pragma unroll
      for (int w = 1; w < 4; ++w) {
        const u64 o = S.pkey[step & 1][w];
        best = o > best ? o : best;
      }
      g = (int)~(unsigned int)best;
    }
    __syncthreads();
    // epilogue: flush all centroid outputs in parallel
    for (int s = t; s < MP; s += 256) {
      const int ci = (b << 10) + s;
      const int p = S.cidx[s];
      const float cx = S.ldspos[p * 3 + 0], cy = S.ldspos[p * 3 + 1], cz = S.ldspos[p * 3 + 2];
      qpos[ci * 3 + 0] = cx; qpos[ci * 3 + 1] = cy; qpos[ci * 3 + 2] = cz;
      dout[OUT1 + (size_t)ci * 3 + 0] = cx;
      dout[OUT1 + (size_t)ci * 3 + 1] = cy;
      dout[OUT1 + (size_t)ci * 3 + 2] = cz;
      dout[OUT2 + ci] = (float)b;
    }
  } else if (bid < NB + 1024) {
    // ================= pk: P = x @ W1[0:64] + b1 (fp16 out), 32 rows/block ==========
    PkS& S = *reinterpret_cast<PkS*>(raw);
    const int r0 = (bid - NB) * 32;
    for (int e = t; e < CIN * D1; e += 256) S.wl[e] = W1[e];
    for (int e = t; e < 32 * CIN; e += 256)
      S.xl[e] = x[(size_t)(r0 + (e >> 6)) * CIN + (e & 63)];
    __syncthreads();
    const int c = t & 127;
    const int rh = t >> 7;           // wave-uniform (waves 0,1 -> 0; waves 2,3 -> 1)
    const float bc = b1[c];
    for (int rr = 0; rr < 32; rr += 2) {
      const int r = rr + rh;
      float acc = bc;
      #pragma unroll
      for (int k = 0; k < CIN; ++k) acc = __fmaf_rn(S.xl[r * CIN + k], S.wl[k * D1 + c], acc);
      P[(size_t)(r0 + r) * D1 + c] = (f16)acc;
    }
  } else {
    // ================= cvt: weight transpose -> fp16 (64 blocks, grid-stride) ========
    const int stride = 64 * 256;
    const int i = (bid - (NB + 1024)) * 256 + t;
    for (int e = i; e < D1 * D2; e += stride) {      // W2t[c][k] = W2[k][c]
      int c = e >> 7, k = e & 127;
      W2t[c * 128 + k] = (f16)W2[k * D2 + c];
    }
    for (int e = i; e < D2 * D3; e += stride) {      // W3t[c][k] = W3[k][c]
      int c = e >> 7, k = e & 127;
      W3t[c * 128 + k] = (f16)W3[k * D3 + c];
    }
    for (int e = i; e < 3 * D1; e += stride) W1b[e] = W1[64 * D1 + e];  // rel rows of W1
  }
}

// ---------------- ball query: 1 wave per centroid, exact k-NN within R ----------------
__launch_bounds__(256)
__global__ void ballq_kernel(const float* __restrict__ pos, const float* __restrict__ qpos,
                             int* __restrict__ nbr) {
  __shared__ unsigned long long list[4][CAP];   // 16KB
  const int t = threadIdx.x;
  const int wv = t >> 6, lane = t & 63;
  const int ci = blockIdx.x * 4 + wv;
  const int b = ci >> 10;
  const int base = b * NP;
  const float qx = qpos[ci * 3 + 0], qy = qpos[ci * 3 + 1], qz = qpos[ci * 3 + 2];
  int cnt = 0;
  for (int chunk = 0; chunk < NP / 64; ++chunk) {
    const int p = chunk * 64 + lane;
    const float x = pos[(size_t)(base + p) * 3 + 0];
    const float y = pos[(size_t)(base + p) * 3 + 1];
    const float z = pos[(size_t)(base + p) * 3 + 2];
    const float dx = __fsub_rn(qx, x), dy = __fsub_rn(qy, y), dz = __fsub_rn(qz, z);
    const float d2 = __fadd_rn(__fadd_rn(__fmul_rn(dx, dx), __fmul_rn(dy, dy)),
                               __fmul_rn(dz, dz));
    const bool in = d2 <= R2F;
    const unsigned long long mask = __ballot(in);
    if (in) {
      const int slot = cnt + __popcll(mask & ((1ull << lane) - 1ull));
      if (slot < CAP)
        list[wv][slot] = ((unsigned long long)__float_as_uint(d2) << 32) | (unsigned int)p;
    }
    cnt += __popcll(mask);
  }
  const int cntc = cnt < CAP ? cnt : CAP;
  for (int s = cntc + lane; s < CAP; s += 64) list[wv][s] = ~0ull;
  __syncthreads();
  // bitonic ascending sort of (d2_bits, idx) -> exact top_k tie-break (lowest idx)
  for (int ks = 2; ks <= CAP; ks <<= 1) {
    for (int jj = ks >> 1; jj > 0; jj >>= 1) {
      for (int i = lane; i < CAP; i += 64) {
        const int partner = i ^ jj;
        if (partner > i) {
          const bool up = ((i & ks) == 0);
          const unsigned long long a = list[wv][i], c = list[wv][partner];
          if (up ? (a > c) : (a < c)) { list[wv][i] = c; list[wv][partner] = a; }
        }
      }
      __syncthreads();
    }
  }
  const unsigned long long e = list[wv][lane];
  const int idx = (int)(e & 0xFFFFFFFFull);
  nbr[(ci << 6) + lane] = (lane < cntc) ? idx : -1;
}

// ---------------- fused MLP + max aggregation: 1 block (4 waves) per centroid ----------------
__launch_bounds__(256)
__global__ void mlp_kernel(const float* __restrict__ pos, const float* __restrict__ qpos,
                           const int* __restrict__ nbr, const f16* __restrict__ P,
                           const float* __restrict__ W1b, const f16* __restrict__ W2t,
                           const float* __restrict__ b2c, const f16* __restrict__ W3t,
                           const float* __restrict__ b3c, float* __restrict__ out) {
  __shared__ f16 h1s[64 * 128];   // 16KB, element (r,k) at r*128 + (k ^ ((r&7)<<3))
  __shared__ f16 h2s[64 * 128];   // 16KB, same swizzle
  const int ci = blockIdx.x;
  const int base = (ci >> 10) << 12;
  const int t = threadIdx.x;
  const int lane = t & 63;
  const int wv = __builtin_amdgcn_readfirstlane((int)(t >> 6));
  const int m = lane & 15, qq = lane >> 4;

  const int j = nbr[(ci << 6) + lane];
  const bool valid = j >= 0;
  const int cnt = __popcll(__ballot(valid));   // valid rows are exactly [0, cnt)
  const int j0 = __shfl(j, 0);
  const int jjn = valid ? j : (j0 >= 0 ? j0 : 0);

  const float qx = qpos[ci * 3 + 0], qy = qpos[ci * 3 + 1], qz = qpos[ci * 3 + 2];
  const float rx = pos[(size_t)(base + jjn) * 3 + 0] - qx;
  const float ry = pos[(size_t)(base + jjn) * 3 + 1] - qy;
  const float rz = pos[(size_t)(base + jjn) * 3 + 2] - qz;

  // ---- phase 1: h1 = relu(P[j] + rel@W1b), cols [wv*32, wv*32+32), lane = row ----
  {
    const f16* Prow = P + (size_t)(base + jjn) * D1;
    const int r = lane;
    #pragma unroll
    for (int c8 = 0; c8 < 4; ++c8) {
      const int c0 = wv * 32 + c8 * 8;
      const half8 pv = *(const half8*)(Prow + c0);
      half8 hv;
      #pragma unroll
      for (int u = 0; u < 8; ++u) {
        const int c = c0 + u;
        float v = (float)pv[u] + rx * W1b[c] + ry * W1b[128 + c] + rz * W1b[256 + c];
        hv[u] = (f16)fmaxf(v, 0.0f);
      }
      *(half8*)(h1s + r * 128 + (c0 ^ ((r & 7) << 3))) = hv;
    }
  }
  __syncthreads();

  // ---- phase 2: h2 = relu(h1 @ W2 + b2), wave computes cols [wv*32, wv*32+32) ----
  {
    floatx4 acc[2][4];
    #pragma unroll
    for (int cs = 0; cs < 2; ++cs)
      #pragma unroll
      for (int rt = 0; rt < 4; ++rt) acc[cs][rt] = floatx4{0.f, 0.f, 0.f, 0.f};
    #pragma unroll
    for (int ks = 0; ks < 4; ++ks) {
      const int kk = ks * 32 + qq * 8;
      half8 af[4];
      #pragma unroll
      for (int rt = 0; rt < 4; ++rt) {
        const int r = rt * 16 + m;
        af[rt] = *(const half8*)(h1s + r * 128 + (kk ^ ((r & 7) << 3)));
      }
      half8 bf[2];
      #pragma unroll
      for (int cs = 0; cs < 2; ++cs) {
        const int c = (wv * 2 + cs) * 16 + m;
        bf[cs] = *(const half8*)(W2t + (size_t)c * 128 + kk);
      }
      #pragma unroll
      for (int cs = 0; cs < 2; ++cs)
        #pragma unroll
        for (int rt = 0; rt < 4; ++rt)
          acc[cs][rt] = __builtin_amdgcn_mfma_f32_16x16x32_f16(af[rt], bf[cs], acc[cs][rt], 0, 0, 0);
    }
    #pragma unroll
    for (int cs = 0; cs < 2; ++cs) {
      const int c = (wv * 2 + cs) * 16 + m;
      const float bias = b2c[c];
      #pragma unroll
      for (int rt = 0; rt < 4; ++rt) {
        #pragma unroll
        for (int u = 0; u < 4; ++u) {
          const int r = rt * 16 + qq * 4 + u;   // C layout: col=lane&15, row=(lane>>4)*4+u
          h2s[r * 128 + (c ^ ((r & 7) << 3))] = (f16)fmaxf(acc[cs][rt][u] + bias, 0.0f);
        }
      }
    }
  }
  __syncthreads();

  // ---- phase 3: h3 = relu(h2 @ W3 + b3); masked max over rows; wave cols [wv*64,+64) ----
  {
    floatx4 acc[4][4];
    #pragma unroll
    for (int ct = 0; ct < 4; ++ct)
      #pragma unroll
      for (int rt = 0; rt < 4; ++rt) acc[ct][rt] = floatx4{0.f, 0.f, 0.f, 0.f};
    #pragma unroll
    for (int ks = 0; ks < 4; ++ks) {
      const int kk = ks * 32 + qq * 8;
      half8 af[4];
      #pragma unroll
      for (int rt = 0; rt < 4; ++rt) {
        const int r = rt * 16 + m;
        af[rt] = *(const half8*)(h2s + r * 128 + (kk ^ ((r & 7) << 3)));
      }
      half8 bf[4];
      #pragma unroll
      for (int ct = 0; ct < 4; ++ct) {
        const int c = (wv * 4 + ct) * 16 + m;
        bf[ct] = *(const half8*)(W3t + (size_t)c * 128 + kk);
      }
      #pragma unroll
      for (int ct = 0; ct < 4; ++ct)
        #pragma unroll
        for (int rt = 0; rt < 4; ++rt)
          acc[ct][rt] = __builtin_amdgcn_mfma_f32_16x16x32_f16(af[rt], bf[ct], acc[ct][rt], 0, 0, 0);
    }
    #pragma unroll
    for (int ct = 0; ct < 4; ++ct) {
      const int c = (wv * 4 + ct) * 16 + m;
      const float bias = b3c[c];
      float mx = -INFINITY;
      #pragma unroll
      for (int rt = 0; rt < 4; ++rt) {
        #pragma unroll
        for (int u = 0; u < 4; ++u) {
          const int r = rt * 16 + qq * 4 + u;
          float v = fmaxf(acc[ct][rt][u] + bias, 0.0f);
          v = (r < cnt) ? v : -INFINITY;
          mx = fmaxf(mx, v);
        }
      }
      mx = fmaxf(mx, __shfl_xor(mx, 16));
      mx = fmaxf(mx, __shfl_xor(mx, 32));
      mx = (cnt > 0) ? mx : 0.0f;
      if (qq == 0) out[(size_t)ci * D3 + c] = mx;
    }
  }
}

extern "C" void kernel_launch(void* const* d_in, const int* in_sizes, int n_in,
                              void* d_out, int out_size, void* d_ws, size_t ws_size,
                              hipStream_t stream) {
  const float* x   = (const float*)d_in[0];
  const float* pos = (const float*)d_in[1];
  // d_in[2] = batch: layout known (sorted, NP per cloud) -> unused
  const float* W1 = (const float*)d_in[3];
  const float* b1 = (const float*)d_in[4];
  const float* W2 = (const float*)d_in[5];
  const float* b2 = (const float*)d_in[6];
  const float* W3 = (const float*)d_in[7];
  const float* b3 = (const float*)d_in[8];
  float* out = (float*)d_out;

  char* ws = (char*)d_ws;
  f16*   P    = (f16*)  (ws + 0);          // 8,388,608 B
  float* qpos = (float*)(ws + 8388608);    //    98,304 B
  int*   nbr  = (int*)  (ws + 8486912);    // 2,097,152 B
  f16*   W2t  = (f16*)  (ws + 10584064);   //    32,768 B
  f16*   W3t  = (f16*)  (ws + 10616832);   //    65,536 B
  float* W1b  = (float*)(ws + 10682368);   //     1,536 B   (total ~10.2 MB)

  front_kernel<<<NB + 1024 + 64, 256, 0, stream>>>(pos, x, W1, b1, W2, W3,
                                                   qpos, P, W2t, W3t, W1b, out);
  ballq_kernel<<<NC / 4, 256, 0, stream>>>(pos, qpos, nbr);
  mlp_kernel<<<NC, 256, 0, stream>>>(pos, qpos, nbr, P, W1b, W2t, b2, W3t, b3, out);
}

// Round 9
// 835.850 us; speedup vs baseline: 1.1797x; 1.0295x over previous
//
#include <hip/hip_runtime.h>

// PointNet++ SA module on MI355X.
// Pipeline: fused{cvt, pk, FPS} ; ball query ; fused MLP+max.
// Layer1 trick: x_j@W1a precomputed per point (16x reuse); pair-wise part is only rel@W1b.
// Layers 2/3 use v_mfma_f32_16x16x32_f16 (no fp32 MFMA on CDNA4).
// R2/R4: FPS: 4 waves (1/SIMD), DPP f32 max reduce; argmax via ballot+ctz+readlane. PROVEN.
// R5: REGRESSED: f32x2 min/max scalarized (no v_pk_min/max_f32!) + poll-merge lost to barrier.
// R8: fuse {fps | pk | cvt} on disjoint blockIdx ranges: 986 -> 860us, front 585us.
// R9: (a) packed update retry, targeted: f32x2 ONLY for sub/mul/add (v_pk_*_f32 exist),
//     d[] stays scalar, min/max scalar on nd.x/.y — avoids R5's scalarization bloat.
//     (b) ballq as 1-wave (64-thr) blocks: 45 bitonic-sort barriers become single-wave
//     no-ops (they were syncing 4 waves sorting INDEPENDENT lists).

#define NB 8
#define NP 4096
#define MP 1024
#define NC 8192         // NB*MP centroids
#define CIN 64
#define D1 128
#define D2 128
#define D3 256
#define CAP 512         // ball-query candidate capacity (E[count]~137, 32 sigma safe)

static constexpr float R2F = 0.04f;   // (0.2)^2 in f32, bit-identical to jnp promotion

typedef _Float16 f16;
typedef _Float16 half8 __attribute__((ext_vector_type(8)));
typedef float floatx4 __attribute__((ext_vector_type(4)));
typedef float f32x2 __attribute__((ext_vector_type(2)));
typedef unsigned long long u64;

// d_out layout (floats): [NC*256 out][NC*3 pos_out][NC batch_out]
#define OUT1 ((size_t)NC * D3)
#define OUT2 (OUT1 + (size_t)NC * 3)

// ---------------- fused front end: blocks 0-7 FPS, 8-1031 pk, 1032-1095 cvt ----------
template<int CTRL>
__device__ __forceinline__ float dppmax(float v) {
  const int iv = __builtin_bit_cast(int, v);
  const int sh = __builtin_amdgcn_update_dpp(iv, iv, CTRL, 0xf, 0xf, false);
  return fmaxf(v, __builtin_bit_cast(float, sh));
}

struct FpsS { float ldspos[NP * 3]; u64 pkey[2][4]; int cidx[MP]; };   // 53312 B
struct PkS  { float wl[CIN * D1]; float xl[32 * CIN]; };               // 40960 B

__launch_bounds__(256)
__global__ void front_kernel(const float* __restrict__ pos, const float* __restrict__ x,
                             const float* __restrict__ W1, const float* __restrict__ b1,
                             const float* __restrict__ W2, const float* __restrict__ W3,
                             float* __restrict__ qpos, f16* __restrict__ P,
                             f16* __restrict__ W2t, f16* __restrict__ W3t,
                             float* __restrict__ W1b, float* __restrict__ dout) {
  #pragma clang fp contract(off)
  __shared__ __align__(16) char raw[sizeof(FpsS)];
  const int bid = blockIdx.x;
  const int t = threadIdx.x;

  if (bid < NB) {
    // ================= FPS: 1 block (4 waves, 1/SIMD) per cloud =================
    FpsS& S = *reinterpret_cast<FpsS*>(raw);
    const int b = bid;
    const int lane = t & 63, wv = t >> 6;
    for (int e = t; e < NP * 3; e += 256) S.ldspos[e] = pos[(size_t)b * NP * 3 + e];
    __syncthreads();
    // blocked mapping: thread t owns points [t*16, t*16+16) -> lane order == index order
    // coords packed f32x2 (v_pk_add/mul_f32 eligible); d stays SCALAR (no v_pk_min/max)
    f32x2 px[8], py[8], pz[8];
    float d[16];
    #pragma unroll
    for (int i = 0; i < 8; ++i) {
      const int p = t * 16 + 2 * i;
      px[i] = (f32x2){S.ldspos[p * 3 + 0], S.ldspos[p * 3 + 3]};
      py[i] = (f32x2){S.ldspos[p * 3 + 1], S.ldspos[p * 3 + 4]};
      pz[i] = (f32x2){S.ldspos[p * 3 + 2], S.ldspos[p * 3 + 5]};
      d[2 * i] = INFINITY; d[2 * i + 1] = INFINITY;
    }
    int g = 0;
    for (int step = 0; step < MP; ++step) {
      if (t == 0) S.cidx[step] = g;
      const float cx = S.ldspos[g * 3 + 0], cy = S.ldspos[g * 3 + 1], cz = S.ldspos[g * 3 + 2];
      const f32x2 cx2 = cx, cy2 = cy, cz2 = cz;
      // packed sub/mul/add (contract off -> separate rn ops, exact JAX order);
      // scalar min/max on components (free register access)
      float lv = -1.0f;
      #pragma unroll
      for (int i = 0; i < 8; ++i) {
        const f32x2 dx = px[i] - cx2;
        const f32x2 dy = py[i] - cy2;
        const f32x2 dz = pz[i] - cz2;
        const f32x2 nd = (dx * dx + dy * dy) + dz * dz;
        d[2 * i]     = fminf(d[2 * i],     nd.x);
        d[2 * i + 1] = fminf(d[2 * i + 1], nd.y);
        lv = fmaxf(lv, d[2 * i]);
        lv = fmaxf(lv, d[2 * i + 1]);
      }
      // lane-local argmax, lowest-i tie-break (descending overwrite)
      int li = 15;
      #pragma unroll
      for (int i = 14; i >= 0; --i) li = (d[i] == lv) ? i : li;
      // in-wave max via DPP (VALU pipe): result in lane 63
      float wm = lv;
      wm = dppmax<0xB1>(wm);    // quad_perm [1,0,3,2]
      wm = dppmax<0x4E>(wm);    // quad_perm [2,3,0,1]
      wm = dppmax<0x141>(wm);   // row_half_mirror
      wm = dppmax<0x140>(wm);   // row_mirror
      wm = dppmax<0x142>(wm);   // row_bcast:15
      wm = dppmax<0x143>(wm);   // row_bcast:31
      const float M = __builtin_bit_cast(float,
          __builtin_amdgcn_readlane(__builtin_bit_cast(int, wm), 63));
      // wave argmax: lowest lane holding M, then its lowest i
      const u64 bal = __ballot(lv == M);
      const int Ls = (int)__builtin_ctzll(bal);
      const int sli = __builtin_amdgcn_readlane(li, Ls);
      const int gw = ((wv << 6) + Ls) * 16 + sli;   // wave winner global idx
      if (lane == 0)
        S.pkey[step & 1][wv] = ((u64)__float_as_uint(M) << 32) | (unsigned int)~gw;
      __syncthreads();
      // cross-wave: 4 keys, 3 u64 compare-selects (redundant in every thread)
      u64 best = S.pkey[step & 1][0];
      #pragma unroll
      for (int w = 1; w < 4; ++w) {
        const u64 o = S.pkey[step & 1][w];
        best = o > best ? o : best;
      }
      g = (int)~(unsigned int)best;
    }
    __syncthreads();
    // epilogue: flush all centroid outputs in parallel
    for (int s = t; s < MP; s += 256) {
      const int ci = (b << 10) + s;
      const int p = S.cidx[s];
      const float cx = S.ldspos[p * 3 + 0], cy = S.ldspos[p * 3 + 1], cz = S.ldspos[p * 3 + 2];
      qpos[ci * 3 + 0] = cx; qpos[ci * 3 + 1] = cy; qpos[ci * 3 + 2] = cz;
      dout[OUT1 + (size_t)ci * 3 + 0] = cx;
      dout[OUT1 + (size_t)ci * 3 + 1] = cy;
      dout[OUT1 + (size_t)ci * 3 + 2] = cz;
      dout[OUT2 + ci] = (float)b;
    }
  } else if (bid < NB + 1024) {
    // ================= pk: P = x @ W1[0:64] + b1 (fp16 out), 32 rows/block ==========
    PkS& S = *reinterpret_cast<PkS*>(raw);
    const int r0 = (bid - NB) * 32;
    for (int e = t; e < CIN * D1; e += 256) S.wl[e] = W1[e];
    for (int e = t; e < 32 * CIN; e += 256)
      S.xl[e] = x[(size_t)(r0 + (e >> 6)) * CIN + (e & 63)];
    __syncthreads();
    const int c = t & 127;
    const int rh = t >> 7;           // wave-uniform (waves 0,1 -> 0; waves 2,3 -> 1)
    const float bc = b1[c];
    for (int rr = 0; rr < 32; rr += 2) {
      const int r = rr + rh;
      float acc = bc;
      #pragma unroll
      for (int k = 0; k < CIN; ++k) acc = __fmaf_rn(S.xl[r * CIN + k], S.wl[k * D1 + c], acc);
      P[(size_t)(r0 + r) * D1 + c] = (f16)acc;
    }
  } else {
    // ================= cvt: weight transpose -> fp16 (64 blocks, grid-stride) ========
    const int stride = 64 * 256;
    const int i = (bid - (NB + 1024)) * 256 + t;
    for (int e = i; e < D1 * D2; e += stride) {      // W2t[c][k] = W2[k][c]
      int c = e >> 7, k = e & 127;
      W2t[c * 128 + k] = (f16)W2[k * D2 + c];
    }
    for (int e = i; e < D2 * D3; e += stride) {      // W3t[c][k] = W3[k][c]
      int c = e >> 7, k = e & 127;
      W3t[c * 128 + k] = (f16)W3[k * D3 + c];
    }
    for (int e = i; e < 3 * D1; e += stride) W1b[e] = W1[64 * D1 + e];  // rel rows of W1
  }
}

// ---------------- ball query: 1 wave per BLOCK (barriers ~free), exact k-NN within R --
__launch_bounds__(64)
__global__ void ballq_kernel(const float* __restrict__ pos, const float* __restrict__ qpos,
                             int* __restrict__ nbr) {
  __shared__ unsigned long long list[CAP];   // 4KB
  const int lane = threadIdx.x;
  const int ci = blockIdx.x;
  const int b = ci >> 10;
  const int base = b * NP;
  const float qx = qpos[ci * 3 + 0], qy = qpos[ci * 3 + 1], qz = qpos[ci * 3 + 2];
  int cnt = 0;
  for (int chunk = 0; chunk < NP / 64; ++chunk) {
    const int p = chunk * 64 + lane;
    const float x = pos[(size_t)(base + p) * 3 + 0];
    const float y = pos[(size_t)(base + p) * 3 + 1];
    const float z = pos[(size_t)(base + p) * 3 + 2];
    const float dx = __fsub_rn(qx, x), dy = __fsub_rn(qy, y), dz = __fsub_rn(qz, z);
    const float d2 = __fadd_rn(__fadd_rn(__fmul_rn(dx, dx), __fmul_rn(dy, dy)),
                               __fmul_rn(dz, dz));
    const bool in = d2 <= R2F;
    const unsigned long long mask = __ballot(in);
    if (in) {
      const int slot = cnt + __popcll(mask & ((1ull << lane) - 1ull));
      if (slot < CAP)
        list[slot] = ((unsigned long long)__float_as_uint(d2) << 32) | (unsigned int)p;
    }
    cnt += __popcll(mask);
  }
  const int cntc = cnt < CAP ? cnt : CAP;
  for (int s = cntc + lane; s < CAP; s += 64) list[s] = ~0ull;
  __syncthreads();
  // bitonic ascending sort of (d2_bits, idx) -> exact top_k tie-break (lowest idx)
  for (int ks = 2; ks <= CAP; ks <<= 1) {
    for (int jj = ks >> 1; jj > 0; jj >>= 1) {
      for (int i = lane; i < CAP; i += 64) {
        const int partner = i ^ jj;
        if (partner > i) {
          const bool up = ((i & ks) == 0);
          const unsigned long long a = list[i], c = list[partner];
          if (up ? (a > c) : (a < c)) { list[i] = c; list[partner] = a; }
        }
      }
      __syncthreads();
    }
  }
  const unsigned long long e = list[lane];
  const int idx = (int)(e & 0xFFFFFFFFull);
  nbr[(ci << 6) + lane] = (lane < cntc) ? idx : -1;
}

// ---------------- fused MLP + max aggregation: 1 block (4 waves) per centroid ----------------
__launch_bounds__(256)
__global__ void mlp_kernel(const float* __restrict__ pos, const float* __restrict__ qpos,
                           const int* __restrict__ nbr, const f16* __restrict__ P,
                           const float* __restrict__ W1b, const f16* __restrict__ W2t,
                           const float* __restrict__ b2c, const f16* __restrict__ W3t,
                           const float* __restrict__ b3c, float* __restrict__ out) {
  __shared__ f16 h1s[64 * 128];   // 16KB, element (r,k) at r*128 + (k ^ ((r&7)<<3))
  __shared__ f16 h2s[64 * 128];   // 16KB, same swizzle
  const int ci = blockIdx.x;
  const int base = (ci >> 10) << 12;
  const int t = threadIdx.x;
  const int lane = t & 63;
  const int wv = __builtin_amdgcn_readfirstlane((int)(t >> 6));
  const int m = lane & 15, qq = lane >> 4;

  const int j = nbr[(ci << 6) + lane];
  const bool valid = j >= 0;
  const int cnt = __popcll(__ballot(valid));   // valid rows are exactly [0, cnt)
  const int j0 = __shfl(j, 0);
  const int jjn = valid ? j : (j0 >= 0 ? j0 : 0);

  const float qx = qpos[ci * 3 + 0], qy = qpos[ci * 3 + 1], qz = qpos[ci * 3 + 2];
  const float rx = pos[(size_t)(base + jjn) * 3 + 0] - qx;
  const float ry = pos[(size_t)(base + jjn) * 3 + 1] - qy;
  const float rz = pos[(size_t)(base + jjn) * 3 + 2] - qz;

  // ---- phase 1: h1 = relu(P[j] + rel@W1b), cols [wv*32, wv*32+32), lane = row ----
  {
    const f16* Prow = P + (size_t)(base + jjn) * D1;
    const int r = lane;
    #pragma unroll
    for (int c8 = 0; c8 < 4; ++c8) {
      const int c0 = wv * 32 + c8 * 8;
      const half8 pv = *(const half8*)(Prow + c0);
      half8 hv;
      #pragma unroll
      for (int u = 0; u < 8; ++u) {
        const int c = c0 + u;
        float v = (float)pv[u] + rx * W1b[c] + ry * W1b[128 + c] + rz * W1b[256 + c];
        hv[u] = (f16)fmaxf(v, 0.0f);
      }
      *(half8*)(h1s + r * 128 + (c0 ^ ((r & 7) << 3))) = hv;
    }
  }
  __syncthreads();

  // ---- phase 2: h2 = relu(h1 @ W2 + b2), wave computes cols [wv*32, wv*32+32) ----
  {
    floatx4 acc[2][4];
    #pragma unroll
    for (int cs = 0; cs < 2; ++cs)
      #pragma unroll
      for (int rt = 0; rt < 4; ++rt) acc[cs][rt] = floatx4{0.f, 0.f, 0.f, 0.f};
    #pragma unroll
    for (int ks = 0; ks < 4; ++ks) {
      const int kk = ks * 32 + qq * 8;
      half8 af[4];
      #pragma unroll
      for (int rt = 0; rt < 4; ++rt) {
        const int r = rt * 16 + m;
        af[rt] = *(const half8*)(h1s + r * 128 + (kk ^ ((r & 7) << 3)));
      }
      half8 bf[2];
      #pragma unroll
      for (int cs = 0; cs < 2; ++cs) {
        const int c = (wv * 2 + cs) * 16 + m;
        bf[cs] = *(const half8*)(W2t + (size_t)c * 128 + kk);
      }
      #pragma unroll
      for (int cs = 0; cs < 2; ++cs)
        #pragma unroll
        for (int rt = 0; rt < 4; ++rt)
          acc[cs][rt] = __builtin_amdgcn_mfma_f32_16x16x32_f16(af[rt], bf[cs], acc[cs][rt], 0, 0, 0);
    }
    #pragma unroll
    for (int cs = 0; cs < 2; ++cs) {
      const int c = (wv * 2 + cs) * 16 + m;
      const float bias = b2c[c];
      #pragma unroll
      for (int rt = 0; rt < 4; ++rt) {
        #pragma unroll
        for (int u = 0; u < 4; ++u) {
          const int r = rt * 16 + qq * 4 + u;   // C layout: col=lane&15, row=(lane>>4)*4+u
          h2s[r * 128 + (c ^ ((r & 7) << 3))] = (f16)fmaxf(acc[cs][rt][u] + bias, 0.0f);
        }
      }
    }
  }
  __syncthreads();

  // ---- phase 3: h3 = relu(h2 @ W3 + b3); masked max over rows; wave cols [wv*64,+64) ----
  {
    floatx4 acc[4][4];
    #pragma unroll
    for (int ct = 0; ct < 4; ++ct)
      #pragma unroll
      for (int rt = 0; rt < 4; ++rt) acc[ct][rt] = floatx4{0.f, 0.f, 0.f, 0.f};
    #pragma unroll
    for (int ks = 0; ks < 4; ++ks) {
      const int kk = ks * 32 + qq * 8;
      half8 af[4];
      #pragma unroll
      for (int rt = 0; rt < 4; ++rt) {
        const int r = rt * 16 + m;
        af[rt] = *(const half8*)(h2s + r * 128 + (kk ^ ((r & 7) << 3)));
      }
      half8 bf[4];
      #pragma unroll
      for (int ct = 0; ct < 4; ++ct) {
        const int c = (wv * 4 + ct) * 16 + m;
        bf[ct] = *(const half8*)(W3t + (size_t)c * 128 + kk);
      }
      #pragma unroll
      for (int ct = 0; ct < 4; ++ct)
        #pragma unroll
        for (int rt = 0; rt < 4; ++rt)
          acc[ct][rt] = __builtin_amdgcn_mfma_f32_16x16x32_f16(af[rt], bf[ct], acc[ct][rt], 0, 0, 0);
    }
    #pragma unroll
    for (int ct = 0; ct < 4; ++ct) {
      const int c = (wv * 4 + ct) * 16 + m;
      const float bias = b3c[c];
      float mx = -INFINITY;
      #pragma unroll
      for (int rt = 0; rt < 4; ++rt) {
        #pragma unroll
        for (int u = 0; u < 4; ++u) {
          const int r = rt * 16 + qq * 4 + u;
          float v = fmaxf(acc[ct][rt][u] + bias, 0.0f);
          v = (r < cnt) ? v : -INFINITY;
          mx = fmaxf(mx, v);
        }
      }
      mx = fmaxf(mx, __shfl_xor(mx, 16));
      mx = fmaxf(mx, __shfl_xor(mx, 32));
      mx = (cnt > 0) ? mx : 0.0f;
      if (qq == 0) out[(size_t)ci * D3 + c] = mx;
    }
  }
}

extern "C" void kernel_launch(void* const* d_in, const int* in_sizes, int n_in,
                              void* d_out, int out_size, void* d_ws, size_t ws_size,
                              hipStream_t stream) {
  const float* x   = (const float*)d_in[0];
  const float* pos = (const float*)d_in[1];
  // d_in[2] = batch: layout known (sorted, NP per cloud) -> unused
  const float* W1 = (const float*)d_in[3];
  const float* b1 = (const float*)d_in[4];
  const float* W2 = (const float*)d_in[5];
  const float* b2 = (const float*)d_in[6];
  const float* W3 = (const float*)d_in[7];
  const float* b3 = (const float*)d_in[8];
  float* out = (float*)d_out;

  char* ws = (char*)d_ws;
  f16*   P    = (f16*)  (ws + 0);          // 8,388,608 B
  float* qpos = (float*)(ws + 8388608);    //    98,304 B
  int*   nbr  = (int*)  (ws + 8486912);    // 2,097,152 B
  f16*   W2t  = (f16*)  (ws + 10584064);   //    32,768 B
  f16*   W3t  = (f16*)  (ws + 10616832);   //    65,536 B
  float* W1b  = (float*)(ws + 10682368);   //     1,536 B   (total ~10.2 MB)

  front_kernel<<<NB + 1024 + 64, 256, 0, stream>>>(pos, x, W1, b1, W2, W3,
                                                   qpos, P, W2t, W3t, W1b, out);
  ballq_kernel<<<NC, 64, 0, stream>>>(pos, qpos, nbr);
  mlp_kernel<<<NC, 256, 0, stream>>>(pos, qpos, nbr, P, W1b, W2t, b2, W3t, b3, out);
}